// Round 5
// baseline (90.174 us; speedup 1.0000x reference)
//
#include <hip/hip_runtime.h>
#include <hip/hip_cooperative_groups.h>
#include <stdint.h>

namespace cg = cooperative_groups;

#define NF 24
#define FD 2000
#define VOCABSZ 48000
#define ED 64
#define H1D 64
#define H2D 32
#define NPAIR 276
#define BATCH 4096
#define NSEL 16
#define NTILE 256            // BATCH/16
#define PBASE 49152          // byte offset of P region (after 48KB emb)
#define SCB   147456         // byte offset of scores f16 region (after 96KB P)
#define MEANB 156288         // byte offset of means f32 [276]
#define SELB  157392         // byte offset of sel i32 [16]
#define IJB   157456         // byte offset of pairIJ u16 [276]

typedef _Float16 f16x8 __attribute__((ext_vector_type(8)));
typedef float f32x4 __attribute__((ext_vector_type(4)));

union U4 { f16x8 v; uint32_t u[4]; uint4 q; };

__device__ __forceinline__ uint32_t pkrtz(float lo, float hi){
  uint32_t r; asm("v_cvt_pkrtz_f16_f32 %0, %1, %2" : "=v"(r) : "v"(lo), "v"(hi)); return r;
}
__device__ __forceinline__ uint32_t pk_add(uint32_t a, uint32_t b){
  uint32_t r; asm("v_pk_add_f16 %0, %1, %2" : "=v"(r) : "v"(a), "v"(b)); return r;
}
__device__ __forceinline__ uint32_t pk_relu(uint32_t a){
  uint32_t r; asm("v_pk_max_f16 %0, %1, %2" : "=v"(r) : "v"(a), "v"(0u)); return r;
}

// ============ single fused cooperative kernel ============
__global__ __launch_bounds__(512) void k_all(
    const int* __restrict__ x, const float* __restrict__ tables,
    const float* __restrict__ w1, const float* __restrict__ b1,
    const float* __restrict__ w2, const float* __restrict__ b2,
    const float* __restrict__ w3, const float* __restrict__ b3,
    const float* __restrict__ fc_w, const float* __restrict__ fc_b,
    const float* __restrict__ proj_w, const float* __restrict__ proj_b,
    const float* __restrict__ bias,
    float* __restrict__ part, float* __restrict__ out){
  __shared__ __align__(16) char smem[158368];
  float* means_lds = (float*)(smem + MEANB);
  int*   sel_lds   = (int*)(smem + SELB);
  unsigned short* pairIJ = (unsigned short*)(smem + IJB);

  const int tid  = threadIdx.x;
  const int bt   = blockIdx.x;
  const int lane = tid & 63;
  const int w    = tid >> 6;
  const int n    = lane & 15;
  const int kg   = lane >> 4;

  // scalar consts
  const float b3v = b3[0];
  const float fcb = fc_b[0], pjb = proj_b[0], bsv = bias[0];

  // ---- w1 B-frags + folded b1 (phase B operands) ----
  const int isPt = (w < 4);
  const int o = 16*(w & 3) + n;
  U4 wp0, wp1;
  {
    const float* wsrc = w1 + (size_t)(isPt ? 0 : ED)*H1D + o;
    #pragma unroll
    for(int j=0;j<8;j++) wp0.v[j] = (_Float16)wsrc[(kg*8+j)*H1D];
    #pragma unroll
    for(int j=0;j<8;j++) wp1.v[j] = (_Float16)wsrc[(32+kg*8+j)*H1D];
  }
  const float b1v = isPt ? b1[o] : 0.f;

  // ---- w2/b2/w3 frags (phase C operands) ----
  U4 wf[2][2];
  #pragma unroll
  for(int kh=0;kh<2;kh++)
    #pragma unroll
    for(int nh=0;nh<2;nh++)
      #pragma unroll
      for(int q2=0;q2<4;q2++){
        float lo = w2[(kg*8 + 2*q2     + 32*kh)*H2D + n + 16*nh];
        float hi = w2[(kg*8 + 2*q2 + 1 + 32*kh)*H2D + n + 16*nh];
        wf[kh][nh].u[q2] = pkrtz(lo, hi);
      }
  const float b2v0 = b2[n], b2v1 = b2[n+16];
  const float w3v0 = w3[n], w3v1 = w3[n+16];

  // ---- pair -> (i,j) lookup ----
  if(tid < NPAIR){
    int ii=0, rem=tid;
    while(rem >= NF-1-ii){ rem -= NF-1-ii; ii++; }
    pairIJ[tid] = (unsigned short)((ii<<8) | (ii+1+rem));
  }

  // ---- phase A: gather 16 rows x 24 fields -> f16 LDS (swizzled) ----
  #pragma unroll
  for(int i=0;i<6;i++){
    int c = i*512 + tid;          // 0..3071
    int rid = c >> 3;             // f*16 + b
    int qc = c & 7;               // 16B (8 f16) chunk
    int f = rid >> 4, b = rid & 15;
    int xv = x[(bt*16 + b)*NF + f];
    const float4* rp = (const float4*)(tables + ((size_t)f*VOCABSZ + (size_t)f*FD + (size_t)xv)*ED + qc*8);
    float4 v0 = rp[0], v1 = rp[1];
    uint4 pk;
    pk.x = pkrtz(v0.x, v0.y); pk.y = pkrtz(v0.z, v0.w);
    pk.z = pkrtz(v1.x, v1.y); pk.w = pkrtz(v1.z, v1.w);
    uint32_t db = ((uint32_t)(f*2048 + b*128 + qc*16)) ^ ((uint32_t)(b&7)<<4);
    *(uint4*)(smem + db) = pk;
  }
  __syncthreads();

  // ---- phase B: P = emb @ w1half (+b1) via MFMA, pack f16 into LDS ----
  {
    const uint32_t rswz = ((uint32_t)(n&7))<<4;
    const int slab0 = isPt ? 0 : 24;
    for(int f=0; f<NF; f++){
      U4 a0, a1;
      a0.q = *(const uint4*)(smem + (((uint32_t)(f*2048 + n*128      + kg*16)) ^ rswz));
      a1.q = *(const uint4*)(smem + (((uint32_t)(f*2048 + n*128 + 64 + kg*16)) ^ rswz));
      f32x4 acc = {b1v, b1v, b1v, b1v};
      acc = __builtin_amdgcn_mfma_f32_16x16x32_f16(a0.v, wp0.v, acc, 0,0,0);
      acc = __builtin_amdgcn_mfma_f32_16x16x32_f16(a1.v, wp1.v, acc, 0,0,0);
      int sl = slab0 + f;
      #pragma unroll
      for(int r=0;r<4;r++){
        float up = __shfl_xor(acc[r], 1, 64);
        if((lane & 1) == 0){
          int bo = kg*4 + r;
          int k2 = 8*(w&3) + (n>>1);
          uint32_t db = ((uint32_t)(PBASE + sl*2048 + bo*128 + k2*4)) ^ ((uint32_t)(bo&7)<<4);
          *(uint32_t*)(smem + db) = pkrtz(acc[r], up);
        }
      }
    }
  }
  __syncthreads();

  // ---- phase C: pair loop; scores -> LDS f16; per-tile partial sums -> global part ----
  {
    int p0, np;
    if(w < 4){ np = 35; p0 = w*35; } else { np = 34; p0 = 140 + (w-4)*34; }
    int ii = 0, rem = p0;
    while(rem >= (NF-1-ii)){ rem -= (NF-1-ii); ii++; }
    int jj = ii + 1 + rem;

    const uint32_t aswz = ((uint32_t)(n&7))<<4;
    const uint32_t rowoff = (uint32_t)n*128;
    const uint32_t qoff = (uint32_t)kg*16;

    for(int t=0;t<np;t++){
      int p = p0 + t;
      uint32_t tb = (uint32_t)(PBASE + ii*2048) + rowoff;
      uint32_t ub = (uint32_t)(PBASE + (24+jj)*2048) + rowoff;
      uint4 a0 = *(const uint4*)(smem + ((tb + qoff     ) ^ aswz));
      uint4 a1 = *(const uint4*)(smem + ((tb + qoff + 64 ) ^ aswz));
      uint4 c0 = *(const uint4*)(smem + ((ub + qoff     ) ^ aswz));
      uint4 c1 = *(const uint4*)(smem + ((ub + qoff + 64 ) ^ aswz));

      U4 h0, h1;
      h0.u[0]=pk_relu(pk_add(a0.x,c0.x)); h0.u[1]=pk_relu(pk_add(a0.y,c0.y));
      h0.u[2]=pk_relu(pk_add(a0.z,c0.z)); h0.u[3]=pk_relu(pk_add(a0.w,c0.w));
      h1.u[0]=pk_relu(pk_add(a1.x,c1.x)); h1.u[1]=pk_relu(pk_add(a1.y,c1.y));
      h1.u[2]=pk_relu(pk_add(a1.z,c1.z)); h1.u[3]=pk_relu(pk_add(a1.w,c1.w));

      f32x4 acc0 = {0.f,0.f,0.f,0.f}, acc1 = {0.f,0.f,0.f,0.f};
      acc0 = __builtin_amdgcn_mfma_f32_16x16x32_f16(h0.v, wf[0][0].v, acc0, 0,0,0);
      acc0 = __builtin_amdgcn_mfma_f32_16x16x32_f16(h1.v, wf[1][0].v, acc0, 0,0,0);
      acc1 = __builtin_amdgcn_mfma_f32_16x16x32_f16(h0.v, wf[0][1].v, acc1, 0,0,0);
      acc1 = __builtin_amdgcn_mfma_f32_16x16x32_f16(h1.v, wf[1][1].v, acc1, 0,0,0);

      float vsum[4];
      #pragma unroll
      for(int r=0;r<4;r++){
        float v0 = acc0[r] + b2v0; v0 = v0>0.f?v0:0.f;
        float v1 = acc1[r] + b2v1; v1 = v1>0.f?v1:0.f;
        float s = v0*w3v0 + v1*w3v1;
        #pragma unroll
        for(int m=1;m<16;m<<=1) s += __shfl_xor(s, m, 64);
        vsum[r] = s;
      }
      if(n == 0){
        uint32_t lo = pkrtz(vsum[0]+b3v, vsum[1]+b3v);
        uint32_t hi = pkrtz(vsum[2]+b3v, vsum[3]+b3v);
        *(uint2*)(smem + SCB + p*32 + kg*8) = make_uint2(lo, hi);
      }
      float ps = vsum[0]+vsum[1]+vsum[2]+vsum[3];
      ps += __shfl_xor(ps, 16, 64);
      ps += __shfl_xor(ps, 32, 64);
      if(lane == 0) part[(size_t)bt*NPAIR + p] = ps + 16.f*b3v;
      if(++jj == NF){ ii++; jj = ii+1; }
    }
  }

  // ---- grid-wide barrier: part fully written ----
  cg::this_grid().sync();

  // ---- phase D (every block, redundant): means + top-16 -> sel_lds ----
  if(tid < NPAIR){
    const float* pp = part + tid;
    float s = 0.f;
    #pragma unroll 8
    for(int i=0;i<NTILE;i++) s += pp[(size_t)i*NPAIR];
    means_lds[tid] = s;
  }
  __syncthreads();
  if(tid < 64){
    int l = tid;
    float v[5];
    #pragma unroll
    for(int q=0;q<5;q++){
      int i = l + q*64;
      v[q] = (i < NPAIR) ? means_lds[i] : -3.0e38f;
    }
    for(int s=0;s<NSEL;s++){
      float bv = v[0]; int bslot = 0;
      #pragma unroll
      for(int q=1;q<5;q++){ if(v[q] > bv){ bv = v[q]; bslot = q; } }
      int bi = l + bslot*64;
      float cv = bv; int ci = bi;
      #pragma unroll
      for(int m=1;m<64;m<<=1){
        float ov = __shfl_xor(cv, m, 64);
        int   oi = __shfl_xor(ci, m, 64);
        if(ov > cv || (ov == cv && oi < ci)){ cv = ov; ci = oi; }
      }
      if(l == 0) sel_lds[s] = ci;
      if(bi == ci) v[bslot] = -3.0e38f;
    }
  }
  __syncthreads();

  // ---- phase E: final output for this block's 16 rows ----
  {
    int row = tid >> 5, l32 = tid & 31;
    int brow = bt*16 + row;
    uint32_t rswz = ((uint32_t)(row&7))<<4;
    float acc0 = 0.f, acc1 = 0.f;
    #pragma unroll
    for(int t=0;t<NSEL;t++){
      int p = sel_lds[t];
      int ij = pairIJ[p];
      int ii = ij >> 8, jj = ij & 255;
      uint32_t ei = *(const uint32_t*)(smem + (((uint32_t)(ii*2048 + row*128 + l32*4)) ^ rswz));
      uint32_t ej = *(const uint32_t*)(smem + (((uint32_t)(jj*2048 + row*128 + l32*4)) ^ rswz));
      float s = (float)(*(const _Float16*)(smem + SCB + p*32 + row*2));
      float e0 = (float)(((const _Float16*)&ei)[0]);
      float e1 = (float)(((const _Float16*)&ei)[1]);
      float f0 = (float)(((const _Float16*)&ej)[0]);
      float f1 = (float)(((const _Float16*)&ej)[1]);
      acc0 += e0*f0*s;
      acc1 += e1*f1*s;
    }
    float2 pw = *(const float2*)(proj_w + l32*2);
    float v = acc0*pw.x + acc1*pw.y;
    if(l32 < NF) v += fc_w[x[brow*NF + l32] + l32*FD];
    #pragma unroll
    for(int m=1;m<32;m<<=1) v += __shfl_xor(v, m, 64);
    if(l32 == 0) out[brow] = v + fcb + pjb + bsv;
  }
}

extern "C" void kernel_launch(void* const* d_in, const int* in_sizes, int n_in,
                              void* d_out, int out_size, void* d_ws, size_t ws_size,
                              hipStream_t stream){
  const int*   x      = (const int*)  d_in[0];
  const float* tables = (const float*)d_in[1];
  const float* fc_w   = (const float*)d_in[2];
  const float* fc_b   = (const float*)d_in[3];
  const float* w1     = (const float*)d_in[4];
  const float* b1     = (const float*)d_in[5];
  const float* w2     = (const float*)d_in[6];
  const float* b2     = (const float*)d_in[7];
  const float* w3     = (const float*)d_in[8];
  const float* b3     = (const float*)d_in[9];
  const float* proj_w = (const float*)d_in[10];
  const float* proj_b = (const float*)d_in[11];
  const float* bias   = (const float*)d_in[12];
  float* out = (float*)d_out;

  float* part = (float*)d_ws;   // 256*276 f32

  void* args[] = {
    (void*)&x, (void*)&tables, (void*)&w1, (void*)&b1, (void*)&w2, (void*)&b2,
    (void*)&w3, (void*)&b3, (void*)&fc_w, (void*)&fc_b, (void*)&proj_w,
    (void*)&proj_b, (void*)&bias, (void*)&part, (void*)&out
  };
  hipLaunchCooperativeKernel((const void*)k_all, dim3(NTILE), dim3(512), args, 0, stream);
}

// Round 6
// 56.347 us; speedup vs baseline: 1.6003x; 1.6003x over previous
//
#include <hip/hip_runtime.h>
#include <stdint.h>

#define NF 24
#define FD 2000
#define VOCABSZ 48000
#define ED 64
#define H1D 64
#define H2D 32
#define NPAIR 276
#define BATCH 4096
#define NSEL 16
#define NTILE 256            // BATCH/16
#define PBASE 49152          // byte offset of P region (after 48KB emb)

typedef _Float16 f16x8 __attribute__((ext_vector_type(8)));
typedef float f32x4 __attribute__((ext_vector_type(4)));

union U4 { f16x8 v; uint32_t u[4]; uint4 q; };

__device__ __forceinline__ uint32_t pkrtz(float lo, float hi){
  uint32_t r; asm("v_cvt_pkrtz_f16_f32 %0, %1, %2" : "=v"(r) : "v"(lo), "v"(hi)); return r;
}
__device__ __forceinline__ uint32_t pk_add(uint32_t a, uint32_t b){
  uint32_t r; asm("v_pk_add_f16 %0, %1, %2" : "=v"(r) : "v"(a), "v"(b)); return r;
}
__device__ __forceinline__ uint32_t pk_relu(uint32_t a){
  uint32_t r; asm("v_pk_max_f16 %0, %1, %2" : "=v"(r) : "v"(a), "v"(0u)); return r;
}

// ============ K1: fused projection + pair-MLP scores (1024 thr, 16 waves) ============
// One block per 16-batch tile. LDS: [0,48KB) emb f16 [f][b][k] swizzled;
// [48KB,144KB) P f16x2 [slab][b][k2] swizzled (slab<24: Pt field, else Pb).
// Wave roles: half=w>>3 (Pt/Pb), oq=(w>>1)&3 (o-quarter), fg=w&1 (field group of 12).
__global__ __launch_bounds__(1024) void k_pair(
    const int* __restrict__ x, const float* __restrict__ tables,
    const float* __restrict__ w1, const float* __restrict__ b1,
    const float* __restrict__ w2, const float* __restrict__ b2,
    const float* __restrict__ w3, const float* __restrict__ b3,
    float* __restrict__ scores, float* __restrict__ part){
  __shared__ __align__(16) char smem[147456];   // 144 KB
  const int tid  = threadIdx.x;
  const int bt   = blockIdx.x;
  const int lane = tid & 63;
  const int w    = tid >> 6;         // 0..15
  const int n    = lane & 15;
  const int kg   = lane >> 4;

  const int half = w >> 3;           // 0: Pt, 1: Pb
  const int oq   = (w >> 1) & 3;
  const int fg   = w & 1;
  const int isPt = (half == 0);
  const float b3v = b3[0];

  // ---- w1 B-frags + folded b1 (phase B operands) ----
  const int o = 16*oq + n;
  U4 wp0, wp1;
  {
    const float* wsrc = w1 + (size_t)(isPt ? 0 : ED)*H1D + o;
    #pragma unroll
    for(int j=0;j<8;j++) wp0.v[j] = (_Float16)wsrc[(kg*8+j)*H1D];
    #pragma unroll
    for(int j=0;j<8;j++) wp1.v[j] = (_Float16)wsrc[(32+kg*8+j)*H1D];
  }
  const float b1v = isPt ? b1[o] : 0.f;

  // ---- w2/b2/w3 frags (phase C operands) ----
  U4 wf[2][2];
  #pragma unroll
  for(int kh=0;kh<2;kh++)
    #pragma unroll
    for(int nh=0;nh<2;nh++)
      #pragma unroll
      for(int q2=0;q2<4;q2++){
        float lo = w2[(kg*8 + 2*q2     + 32*kh)*H2D + n + 16*nh];
        float hi = w2[(kg*8 + 2*q2 + 1 + 32*kh)*H2D + n + 16*nh];
        wf[kh][nh].u[q2] = pkrtz(lo, hi);
      }
  const float b2v0 = b2[n], b2v1 = b2[n+16];
  const float w3v0 = w3[n], w3v1 = w3[n+16];

  // ---- phase A: gather 16 rows x 24 fields -> f16 LDS (swizzled) ----
  #pragma unroll
  for(int i=0;i<3;i++){
    int c = i*1024 + tid;         // 0..3071
    int rid = c >> 3;             // f*16 + b
    int qc = c & 7;               // 16B (8 f16) chunk
    int f = rid >> 4, b = rid & 15;
    int xv = x[(bt*16 + b)*NF + f];
    const float4* rp = (const float4*)(tables + ((size_t)f*VOCABSZ + (size_t)f*FD + (size_t)xv)*ED + qc*8);
    float4 v0 = rp[0], v1 = rp[1];
    uint4 pk;
    pk.x = pkrtz(v0.x, v0.y); pk.y = pkrtz(v0.z, v0.w);
    pk.z = pkrtz(v1.x, v1.y); pk.w = pkrtz(v1.z, v1.w);
    uint32_t db = ((uint32_t)(f*2048 + b*128 + qc*16)) ^ ((uint32_t)(b&7)<<4);
    *(uint4*)(smem + db) = pk;
  }
  __syncthreads();

  // ---- phase B: P = emb @ w1half (+b1) via MFMA (12 fields per wave) ----
  {
    const uint32_t rswz = ((uint32_t)(n&7))<<4;
    const int slab0 = isPt ? 0 : 24;
    for(int ff=0; ff<12; ff++){
      int f = fg*12 + ff;
      U4 a0, a1;
      a0.q = *(const uint4*)(smem + (((uint32_t)(f*2048 + n*128      + kg*16)) ^ rswz));
      a1.q = *(const uint4*)(smem + (((uint32_t)(f*2048 + n*128 + 64 + kg*16)) ^ rswz));
      f32x4 acc = {b1v, b1v, b1v, b1v};
      acc = __builtin_amdgcn_mfma_f32_16x16x32_f16(a0.v, wp0.v, acc, 0,0,0);
      acc = __builtin_amdgcn_mfma_f32_16x16x32_f16(a1.v, wp1.v, acc, 0,0,0);
      int sl = slab0 + f;
      #pragma unroll
      for(int r=0;r<4;r++){
        float up = __shfl_xor(acc[r], 1, 64);
        if((lane & 1) == 0){
          int bo = kg*4 + r;
          int k2 = 8*oq + (n>>1);
          uint32_t db = ((uint32_t)(PBASE + sl*2048 + bo*128 + k2*4)) ^ ((uint32_t)(bo&7)<<4);
          *(uint32_t*)(smem + db) = pkrtz(acc[r], up);
        }
      }
    }
  }
  __syncthreads();

  // ---- phase C: pair loop over 16 waves (17-18 pairs each) ----
  {
    int p0, np;
    if(w < 4){ np = 18; p0 = w*18; } else { np = 17; p0 = 72 + (w-4)*17; }
    int ii = 0, rem = p0;
    while(rem >= (NF-1-ii)){ rem -= (NF-1-ii); ii++; }
    int jj = ii + 1 + rem;

    const uint32_t aswz = ((uint32_t)(n&7))<<4;
    const uint32_t rowoff = (uint32_t)n*128;
    const uint32_t qoff = (uint32_t)kg*16;

    for(int t=0;t<np;t++){
      int p = p0 + t;
      uint32_t tb = (uint32_t)(PBASE + ii*2048) + rowoff;
      uint32_t ub = (uint32_t)(PBASE + (24+jj)*2048) + rowoff;
      uint4 a0 = *(const uint4*)(smem + ((tb + qoff     ) ^ aswz));
      uint4 a1 = *(const uint4*)(smem + ((tb + qoff + 64 ) ^ aswz));
      uint4 c0 = *(const uint4*)(smem + ((ub + qoff     ) ^ aswz));
      uint4 c1 = *(const uint4*)(smem + ((ub + qoff + 64 ) ^ aswz));

      U4 h0, h1;
      h0.u[0]=pk_relu(pk_add(a0.x,c0.x)); h0.u[1]=pk_relu(pk_add(a0.y,c0.y));
      h0.u[2]=pk_relu(pk_add(a0.z,c0.z)); h0.u[3]=pk_relu(pk_add(a0.w,c0.w));
      h1.u[0]=pk_relu(pk_add(a1.x,c1.x)); h1.u[1]=pk_relu(pk_add(a1.y,c1.y));
      h1.u[2]=pk_relu(pk_add(a1.z,c1.z)); h1.u[3]=pk_relu(pk_add(a1.w,c1.w));

      f32x4 acc0 = {0.f,0.f,0.f,0.f}, acc1 = {0.f,0.f,0.f,0.f};
      acc0 = __builtin_amdgcn_mfma_f32_16x16x32_f16(h0.v, wf[0][0].v, acc0, 0,0,0);
      acc0 = __builtin_amdgcn_mfma_f32_16x16x32_f16(h1.v, wf[1][0].v, acc0, 0,0,0);
      acc1 = __builtin_amdgcn_mfma_f32_16x16x32_f16(h0.v, wf[0][1].v, acc1, 0,0,0);
      acc1 = __builtin_amdgcn_mfma_f32_16x16x32_f16(h1.v, wf[1][1].v, acc1, 0,0,0);

      float vsum[4];
      #pragma unroll
      for(int r=0;r<4;r++){
        float v0 = acc0[r] + b2v0; v0 = v0>0.f?v0:0.f;
        float v1 = acc1[r] + b2v1; v1 = v1>0.f?v1:0.f;
        float s = v0*w3v0 + v1*w3v1;
        #pragma unroll
        for(int m=1;m<16;m<<=1) s += __shfl_xor(s, m, 64);
        vsum[r] = s;
      }
      if(n == 0){
        float* sp = scores + (size_t)p*BATCH + bt*16 + kg*4;
        sp[0]=vsum[0]+b3v; sp[1]=vsum[1]+b3v; sp[2]=vsum[2]+b3v; sp[3]=vsum[3]+b3v;
      }
      float ps = vsum[0]+vsum[1]+vsum[2]+vsum[3];
      ps += __shfl_xor(ps, 16, 64);
      ps += __shfl_xor(ps, 32, 64);
      if(lane == 0) part[(size_t)p*NTILE + bt] = ps + 16.f*b3v;   // [pair][tile]
      if(++jj == NF){ ii++; jj = ii+1; }
    }
  }
}

// ============ K2: fused select (redundant per block) + final output ============
__global__ __launch_bounds__(1024) void k_final(
    const int* __restrict__ x, const float* __restrict__ tables,
    const float* __restrict__ scores, const float* __restrict__ part,
    const float* __restrict__ fc_w, const float* __restrict__ fc_b,
    const float* __restrict__ proj_w, const float* __restrict__ proj_b,
    const float* __restrict__ bias, float* __restrict__ out){
  __shared__ float means[NPAIR];
  __shared__ int sel[NSEL];
  __shared__ unsigned short pairIJ[NPAIR];
  int tid = threadIdx.x;
  int bt = blockIdx.x;

  // means (deterministic fixed-order sum; contiguous 1KB run per thread)
  if(tid < NPAIR){
    int ii=0, rem=tid;
    while(rem >= NF-1-ii){ rem -= NF-1-ii; ii++; }
    pairIJ[tid] = (unsigned short)((ii<<8) | (ii+1+rem));
    const float4* pp = (const float4*)(part + (size_t)tid*NTILE);
    float4 s4 = {0.f,0.f,0.f,0.f};
    #pragma unroll 8
    for(int i=0;i<NTILE/4;i++){
      float4 v = pp[i];
      s4.x += v.x; s4.y += v.y; s4.z += v.z; s4.w += v.w;
    }
    means[tid] = (s4.x + s4.y) + (s4.z + s4.w);
  }
  __syncthreads();
  if(tid < 64){
    int l = tid;
    float v[5];
    #pragma unroll
    for(int q=0;q<5;q++){
      int i = l + q*64;
      v[q] = (i < NPAIR) ? means[i] : -3.0e38f;
    }
    for(int s=0;s<NSEL;s++){
      float bv = v[0]; int bslot = 0;
      #pragma unroll
      for(int q=1;q<5;q++){ if(v[q] > bv){ bv = v[q]; bslot = q; } }
      int bi = l + bslot*64;
      float cv = bv; int ci = bi;
      #pragma unroll
      for(int m=1;m<64;m<<=1){
        float ov = __shfl_xor(cv, m, 64);
        int   oi = __shfl_xor(ci, m, 64);
        if(ov > cv || (ov == cv && oi < ci)){ cv = ov; ci = oi; }
      }
      if(l == 0) sel[s] = ci;
      if(bi == ci) v[bslot] = -3.0e38f;
    }
  }
  __syncthreads();

  // final: 16 rows per block, one wave per row
  int row = tid >> 6, lane = tid & 63;
  int brow = bt*16 + row;
  float acc = 0.f;
  #pragma unroll
  for(int t=0;t<NSEL;t++){
    int p = sel[t];
    int ij = pairIJ[p];
    int ii = ij >> 8, jj = ij & 255;
    int xi = x[brow*NF+ii], xj = x[brow*NF+jj];
    float ei = tables[((size_t)ii*VOCABSZ + (size_t)ii*FD + (size_t)xi)*ED + lane];
    float ej = tables[((size_t)jj*VOCABSZ + (size_t)jj*FD + (size_t)xj)*ED + lane];
    float s = scores[(size_t)p*BATCH + brow];
    acc += ei*ej*s;
  }
  float v = acc * proj_w[lane];
  if(lane < NF) v += fc_w[x[brow*NF+lane] + lane*FD];
  #pragma unroll
  for(int m=1;m<64;m<<=1) v += __shfl_xor(v, m, 64);
  if(lane == 0) out[brow] = v + fc_b[0] + proj_b[0] + bias[0];
}

extern "C" void kernel_launch(void* const* d_in, const int* in_sizes, int n_in,
                              void* d_out, int out_size, void* d_ws, size_t ws_size,
                              hipStream_t stream){
  const int*   x      = (const int*)  d_in[0];
  const float* tables = (const float*)d_in[1];
  const float* fc_w   = (const float*)d_in[2];
  const float* fc_b   = (const float*)d_in[3];
  const float* w1     = (const float*)d_in[4];
  const float* b1     = (const float*)d_in[5];
  const float* w2     = (const float*)d_in[6];
  const float* b2     = (const float*)d_in[7];
  const float* w3     = (const float*)d_in[8];
  const float* b3     = (const float*)d_in[9];
  const float* proj_w = (const float*)d_in[10];
  const float* proj_b = (const float*)d_in[11];
  const float* bias   = (const float*)d_in[12];
  float* out = (float*)d_out;

  float* scores = (float*)d_ws;                        // 276*4096 f32
  float* part   = scores + (size_t)NPAIR*BATCH;        // 276*256 f32 [pair][tile]

  k_pair<<<NTILE, 1024, 0, stream>>>(x, tables, w1, b1, w2, b2, w3, b3, scores, part);
  k_final<<<NTILE, 1024, 0, stream>>>(x, tables, scores, part, fc_w, fc_b, proj_w, proj_b, bias, out);
}